// Round 6
// baseline (216.239 us; speedup 1.0000x reference)
//
#include <hip/hip_runtime.h>
#include <math.h>

constexpr int Bn = 64, Lc = 1024, Lq = 128, Dd = 128;

typedef __attribute__((ext_vector_type(8))) short short8_t;  // 8 bf16
typedef __attribute__((ext_vector_type(4))) short short4_t;  // 4 bf16
typedef __attribute__((ext_vector_type(4))) float f32x4;

__device__ __forceinline__ short f2bf(float x) {
    unsigned u = __float_as_uint(x);
    u += 0x7FFFu + ((u >> 16) & 1u);   // round-to-nearest-even
    return (short)(u >> 16);
}

constexpr int AS = 132;   // [row][d] LDS stride (shorts)
constexpr int CTS = 68;   // kT C^T staging stride (shorts)
constexpr int PS = 68;    // kT P^T tile stride (shorts)
constexpr int TBF = 36;   // kT f32 out-transpose stride (floats)

// ============ kT: Q prep/export + recompute E^T + T-partials; i-range split across 2 halves ============
// grid (512) = (2 half x 4 jq x 64 b), 512 threads, 2 blocks/CU.
__global__ __launch_bounds__(512) void kT(
    const float* __restrict__ C, const float* __restrict__ Q,
    const int* __restrict__ Cmask, const int* __restrict__ Qmask,
    const float* __restrict__ w_c, const float* __restrict__ w_q,
    const float* __restrict__ w_mul, const float* __restrict__ bias,
    short* __restrict__ Q16, short* __restrict__ QT16,
    float* __restrict__ s1f, float* __restrict__ Tpart, float* __restrict__ colpart)
{
    __shared__ short Qs[32 * AS];
    __shared__ short CWs[128 * TBF * 2];   // staging: [64][AS] shorts; epilogue: f32 [128][TBF]
    __shared__ short CTs[128 * CTS];       // masked C^T chunk (128 d x 64 i)
    __shared__ short Ps[32 * PS];          // P^T tile (32 j x 64 i)
    __shared__ float s1bL[32], qmL[32], s0L[64], cmL[64];
    __shared__ float colAcc[128];

    int n = blockIdx.x;
    int b = (n & 7) * 8 + ((n >> 3) & 7);
    int rest = n >> 6, jq = rest & 3, half = rest >> 2;
    int tid = threadIdx.x, w = tid >> 6, lane = tid & 63;
    int lm = lane & 15, quad = lane >> 4;
    int jh = w & 1, ih = w >> 1;
    int hh = lane >> 5;                    // == iS & 1 (i-parity of this lane)

    // ---- phase 0: Q f32 slice -> Qs bf16 (+ Q16 export by half0) + s1 + qm ----
    {
        int j = tid >> 4, d4 = tid & 15;
        const float4* Q4 = (const float4*)(Q + ((size_t)(b * Lq + jq * 32 + j)) * Dd);
        float4 v0 = Q4[d4], v1 = Q4[d4 + 16];
        short4_t q0, q1;
        q0[0]=f2bf(v0.x); q0[1]=f2bf(v0.y); q0[2]=f2bf(v0.z); q0[3]=f2bf(v0.w);
        q1[0]=f2bf(v1.x); q1[1]=f2bf(v1.y); q1[2]=f2bf(v1.z); q1[3]=f2bf(v1.w);
        *(short4_t*)&Qs[j * AS + d4 * 4] = q0;
        *(short4_t*)&Qs[j * AS + (d4 + 16) * 4] = q1;
        if (half == 0) {
            *(short4_t*)&Q16[((size_t)(b * Lq + jq * 32 + j)) * Dd + d4 * 4] = q0;
            *(short4_t*)&Q16[((size_t)(b * Lq + jq * 32 + j)) * Dd + (d4 + 16) * 4] = q1;
        }
        float4 wq0 = ((const float4*)w_q)[d4], wq1 = ((const float4*)w_q)[d4 + 16];
        float dot = v0.x*wq0.x + v0.y*wq0.y + v0.z*wq0.z + v0.w*wq0.w
                  + v1.x*wq1.x + v1.y*wq1.y + v1.z*wq1.z + v1.w*wq1.w;
        #pragma unroll
        for (int off = 1; off < 16; off <<= 1) dot += __shfl_xor(dot, off, 64);
        if (d4 == 0) {
            s1bL[j] = dot + bias[0];
            qmL[j] = (Qmask[b * Lq + jq * 32 + j] != 0) ? 1.0f : 0.0f;
            if (half == 0) s1f[b * Lq + jq * 32 + j] = dot;
        }
    }

    // ---- prefetch first chunk ----
    const float4* Cb4 = (const float4*)(C + (size_t)b * Lc * Dd);
    int iS = tid >> 5, dS = tid & 31;
    float4 wmv = ((const float4*)w_mul)[dS];
    float4 wcv = ((const float4*)w_c)[dS];
    int ic0 = half * 8;
    float4 pc[4]; int pm[4];
    #pragma unroll
    for (int k = 0; k < 4; ++k) {
        int gi = ic0 * 64 + iS + k * 16;
        pc[k] = Cb4[(size_t)gi * 32 + dS];
        pm[k] = Cmask[b * Lc + gi];
    }

    float csum[4] = {0.f, 0.f, 0.f, 0.f};
    f32x4 acc2[2];
    acc2[0] = (f32x4){0.f,0.f,0.f,0.f};
    acc2[1] = (f32x4){0.f,0.f,0.f,0.f};

    for (int ic = ic0; ic < ic0 + 8; ++ic) {
        __syncthreads();
        #pragma unroll
        for (int k = 0; k < 4; ++k) {
            float4 v = pc[k];
            float cm = pm[k] ? 1.0f : 0.0f;
            int i = iS + k * 16;
            short4_t cw;
            cw[0]=f2bf(v.x*wmv.x); cw[1]=f2bf(v.y*wmv.y); cw[2]=f2bf(v.z*wmv.z); cw[3]=f2bf(v.w*wmv.w);
            *(short4_t*)&CWs[i * AS + dS * 4] = cw;
            // paired CT transpose writes: lanes L<->L^32 hold (i, i^1) for same dS.
            // One word exchange -> each half-wave writes 2 short2 rows instead of 4 scalars.
            short4_t cc;
            cc[0]=f2bf(cm*v.x); cc[1]=f2bf(cm*v.y); cc[2]=f2bf(cm*v.z); cc[3]=f2bf(cm*v.w);
            unsigned ux = ((unsigned*)&cc)[0];   // r0 lo, r1 hi
            unsigned uy = ((unsigned*)&cc)[1];   // r2 lo, r3 hi
            unsigned snd = hh ? ux : uy;
            unsigned rcv = (unsigned)__shfl_xor((int)snd, 32, 64);
            unsigned we = hh ? rcv : ux;         // word for even-i, rows 2hh..2hh+1
            unsigned wo = hh ? uy : rcv;         // word for odd-i
            unsigned val0 = (we & 0xFFFFu) | (wo << 16);
            unsigned val1 = (we >> 16) | (wo & 0xFFFF0000u);
            int rowb = dS * 4 + 2 * hh;
            int ibase = i & ~1;
            *(unsigned*)&CTs[rowb * CTS + ibase]       = val0;
            *(unsigned*)&CTs[(rowb + 1) * CTS + ibase] = val1;
            float dot = v.x*wcv.x + v.y*wcv.y + v.z*wcv.z + v.w*wcv.w;
            #pragma unroll
            for (int off = 1; off < 32; off <<= 1) dot += __shfl_xor(dot, off, 64);
            if (dS == 0) { s0L[i] = dot; cmL[i] = cm; }
        }
        if (ic < ic0 + 7) {
            int ibn = (ic + 1) * 64;
            #pragma unroll
            for (int k = 0; k < 4; ++k) {
                pc[k] = Cb4[((size_t)(ibn + iS + k * 16)) * 32 + dS];
                pm[k] = Cmask[b * Lc + ibn + iS + k * 16];
            }
        }
        __syncthreads();

        // S^T tile [32j x 64i] across 8 waves; bit-identical to k3's S (operand swap)
        f32x4 sacc = (f32x4){0.f,0.f,0.f,0.f};
        #pragma unroll
        for (int ks = 0; ks < 4; ++ks) {
            short8_t a = *(short8_t*)&Qs[(jh * 16 + lm) * AS + ks * 32 + quad * 8];
            short8_t bq = *(short8_t*)&CWs[(ih * 16 + lm) * AS + ks * 32 + quad * 8];
            sacc = __builtin_amdgcn_mfma_f32_16x16x32_bf16(a, bq, sacc, 0, 0, 0);
        }
        float s0v = s0L[ih * 16 + lm];
        float cmv = cmL[ih * 16 + lm];
        #pragma unroll
        for (int r = 0; r < 4; ++r) {
            float e = __expf(sacc[r] + s0v + s1bL[jh * 16 + quad * 4 + r]);
            Ps[(jh * 16 + quad * 4 + r) * PS + ih * 16 + lm] = f2bf(e);
            csum[r] += cmv * e;
        }
        __syncthreads();

        // T partial: [16j x 32d] per wave, k = 64 i
        #pragma unroll
        for (int ks = 0; ks < 2; ++ks) {
            short8_t a = *(short8_t*)&Ps[(jh * 16 + lm) * PS + ks * 32 + quad * 8];
            #pragma unroll
            for (int t = 0; t < 2; ++t) {
                short8_t bf = *(short8_t*)&CTs[((ih * 2 + t) * 16 + lm) * CTS + ks * 32 + quad * 8];
                acc2[t] = __builtin_amdgcn_mfma_f32_16x16x32_bf16(a, bf, acc2[t], 0, 0, 0);
            }
        }
    }

    // ---- colsum partial reduce + T-partial f32 transpose via LDS ----
    #pragma unroll
    for (int r = 0; r < 4; ++r) {
        float v = csum[r];
        v += __shfl_xor(v, 1, 64); v += __shfl_xor(v, 2, 64);
        v += __shfl_xor(v, 4, 64); v += __shfl_xor(v, 8, 64);
        if (lm == 0) colAcc[ih * 32 + jh * 16 + quad * 4 + r] = v;
    }
    float* Tbf = (float*)CWs;
    #pragma unroll
    for (int t = 0; t < 2; ++t) {
        int d = (ih * 2 + t) * 16 + lm;
        #pragma unroll
        for (int r = 0; r < 4; ++r)
            Tbf[d * TBF + jh * 16 + quad * 4 + r] = acc2[t][r];
    }
    __syncthreads();
    if (tid < 32)
        colpart[((size_t)(half * Bn + b)) * Lq + jq * 32 + tid] =
            colAcc[tid] + colAcc[32 + tid] + colAcc[64 + tid] + colAcc[96 + tid];
    #pragma unroll
    for (int k = 0; k < 2; ++k) {
        int idx = tid + k * 512;
        int d = idx >> 3, j4 = idx & 7;
        *(float4*)&Tpart[(((size_t)(half * Bn + b)) * Dd + d) * Lq + jq * 32 + j4 * 4] =
            *(float4*)&Tbf[d * TBF + j4 * 4];
    }

    // ---- QT16 export (masked) by half1 ----
    if (half == 1) {
        int d = tid >> 2, j8 = (tid & 3) * 8;
        short8_t o;
        #pragma unroll
        for (int r = 0; r < 8; ++r) {
            int j = j8 + r;
            o[r] = (qmL[j] != 0.f) ? Qs[j * AS + d] : (short)0;
        }
        *(short8_t*)&QT16[((size_t)(b * Dd + d)) * Lq + jq * 32 + j8] = o;
    }
}

// ============ k3: recompute P=exp(S); A=(P@Qm)*rs, Bm=(P@(Tp0+Tp1)*invq)*rs; out ============
__global__ __launch_bounds__(256, 3) void k3_out(
    const short* __restrict__ Q16, const short* __restrict__ QT16,
    const float* __restrict__ Tpart, const float* __restrict__ colpart,
    const float* __restrict__ C, const float* __restrict__ w_mul,
    const float* __restrict__ w_c, const int* __restrict__ Qmask,
    const float* __restrict__ s1f, const float* __restrict__ bias,
    float* __restrict__ out)
{
    __shared__ short Abuf[64 * AS];    // cw, then P (e bf16)
    __shared__ short Bbuf[128 * AS];   // Q -> QTs -> Af32 -> TTs -> Af32
    __shared__ float s0L[64], s1bL[128], qmLf[128], invqL[128];
    float* Af32 = (float*)Bbuf;

    int n = blockIdx.x;
    int b = (n & 7) * 8 + ((n >> 3) & 7);
    int blk = n >> 6;
    int i0 = blk * 64, tid = threadIdx.x;
    int w = tid >> 6, lane = tid & 63, lm = lane & 15, quad = lane >> 4;

    // ---- stage Q16 -> Bbuf; issue QT prefetch (in flight across S-MFMA); C -> cv + cw + s0 ----
    const short8_t* Qg = (const short8_t*)(Q16 + (size_t)b * Lq * Dd);
    #pragma unroll
    for (int k = 0; k < 8; ++k) {
        int idx = tid + k * 256;
        int j = idx >> 4, h = idx & 15;
        *(short8_t*)&Bbuf[j * AS + h * 8] = Qg[idx];
    }
    const short8_t* QTg = (const short8_t*)(QT16 + (size_t)b * Dd * Lq);
    short8_t qtp[8];
    #pragma unroll
    for (int k = 0; k < 8; ++k) qtp[k] = QTg[tid + k * 256];

    const float4* C4 = (const float4*)(C + ((size_t)(b * Lc + i0)) * Dd);
    float4 cv[8];
    #pragma unroll
    for (int k = 0; k < 8; ++k) {
        int idx = tid + k * 256;
        int i = idx >> 5, d4 = idx & 31;
        float4 v = C4[idx];
        cv[k] = v;
        float4 wm = ((const float4*)w_mul)[d4];
        short4_t cw; cw[0]=f2bf(v.x*wm.x); cw[1]=f2bf(v.y*wm.y); cw[2]=f2bf(v.z*wm.z); cw[3]=f2bf(v.w*wm.w);
        *(short4_t*)&Abuf[i * AS + d4 * 4] = cw;
        float4 wc = ((const float4*)w_c)[d4];
        float dot = v.x*wc.x + v.y*wc.y + v.z*wc.z + v.w*wc.w;
        #pragma unroll
        for (int off = 1; off < 32; off <<= 1) dot += __shfl_xor(dot, off, 64);
        if ((tid & 31) == 0) s0L[i] = dot;
    }
    if (tid < 128) {
        float qm = (Qmask[b * Lq + tid] != 0) ? 1.0f : 0.0f;
        qmLf[tid] = qm;
        s1bL[tid] = s1f[b * Lq + tid] + bias[0];
        float cs = colpart[(size_t)b * Lq + tid] + colpart[((size_t)(Bn + b)) * Lq + tid];
        invqL[tid] = (qm != 0.f) ? 1.0f / cs : 0.0f;
    }
    __syncthreads();

    // ---- S = Cw @ Q^T (bit-identical to kT's S^T) ----
    f32x4 acc[8];
    #pragma unroll
    for (int t = 0; t < 8; ++t) acc[t] = (f32x4){0.f,0.f,0.f,0.f};
    #pragma unroll
    for (int ks = 0; ks < 4; ++ks) {
        short8_t a = *(short8_t*)&Abuf[(w * 16 + lm) * AS + ks * 32 + quad * 8];
        #pragma unroll
        for (int jt = 0; jt < 8; ++jt) {
            short8_t bf = *(short8_t*)&Bbuf[(jt * 16 + lm) * AS + ks * 32 + quad * 8];
            acc[jt] = __builtin_amdgcn_mfma_f32_16x16x32_bf16(a, bf, acc[jt], 0, 0, 0);
        }
    }

    // ---- P = exp(S) bf16 -> Abuf (wave-own rows) + local rowsum ----
    float s0v[4];
    #pragma unroll
    for (int r = 0; r < 4; ++r) s0v[r] = s0L[w * 16 + quad * 4 + r];
    float rowpart[4] = {0.f, 0.f, 0.f, 0.f};
    #pragma unroll
    for (int jt = 0; jt < 8; ++jt) {
        int j = jt * 16 + lm;
        float s1b = s1bL[j];
        float qm = qmLf[j];
        #pragma unroll
        for (int r = 0; r < 4; ++r) {
            float e = __expf(acc[jt][r] + s0v[r] + s1b);
            Abuf[(w * 16 + quad * 4 + r) * AS + j] = f2bf(e);
            rowpart[r] += qm * e;
        }
    }
    float rs[4];
    #pragma unroll
    for (int r = 0; r < 4; ++r) {
        float v = rowpart[r];
        v += __shfl_xor(v, 1, 64); v += __shfl_xor(v, 2, 64);
        v += __shfl_xor(v, 4, 64); v += __shfl_xor(v, 8, 64);
        rs[r] = 1.0f / v;
    }
    __syncthreads();

    // ---- write prefetched QTs -> Bbuf; accQ = P @ QT ----
    #pragma unroll
    for (int k = 0; k < 8; ++k) {
        int idx = tid + k * 256;
        int d = idx >> 4, h = idx & 15;
        *(short8_t*)&Bbuf[d * AS + h * 8] = qtp[k];
    }
    __syncthreads();
    f32x4 accQ[8];
    #pragma unroll
    for (int t = 0; t < 8; ++t) accQ[t] = (f32x4){0.f,0.f,0.f,0.f};
    #pragma unroll
    for (int ks = 0; ks < 4; ++ks) {
        short8_t a = *(short8_t*)&Abuf[(w * 16 + lm) * AS + ks * 32 + quad * 8];
        #pragma unroll
        for (int dt = 0; dt < 8; ++dt) {
            short8_t bf = *(short8_t*)&Bbuf[(dt * 16 + lm) * AS + ks * 32 + quad * 8];
            accQ[dt] = __builtin_amdgcn_mfma_f32_16x16x32_bf16(a, bf, accQ[dt], 0, 0, 0);
        }
    }
    __syncthreads();

    // ---- epilogue A: Af32 = accQ*rs; TT half-prefetch under the stores; out C, A, C*A ----
    #pragma unroll
    for (int dt = 0; dt < 8; ++dt)
        #pragma unroll
        for (int r = 0; r < 4; ++r)
            Af32[(w * 16 + quad * 4 + r) * AS + dt * 16 + lm] = accQ[dt][r] * rs[r];
    __syncthreads();

    const float4* T0 = (const float4*)(Tpart + (size_t)b * Dd * Lq);
    const float4* T1 = (const float4*)(Tpart + ((size_t)(Bn + b)) * Dd * Lq);
    float4 t0p[8], t1p[8];
    #pragma unroll
    for (int k = 0; k < 8; ++k) { t0p[k] = T0[tid + k * 256]; t1p[k] = T1[tid + k * 256]; }

    #pragma unroll
    for (int k = 0; k < 8; ++k) {
        int idx = tid + k * 256;
        int i = idx >> 5, d4 = idx & 31;
        float4 av = *(float4*)&Af32[i * AS + d4 * 4];
        float4 c = cv[k];
        size_t base = ((size_t)(b * Lc + i0 + i)) * (4 * Dd) + d4 * 4;
        *(float4*)&out[base]           = c;
        *(float4*)&out[base + Dd]      = av;
        float4 ca; ca.x = c.x*av.x; ca.y = c.y*av.y; ca.z = c.z*av.z; ca.w = c.w*av.w;
        *(float4*)&out[base + 2 * Dd]  = ca;
    }
    __syncthreads();

    // ---- stage TTs -> Bbuf from Tpart halves (k<8 from regs), scaled by invq; accT = P @ T ----
    #pragma unroll
    for (int k = 0; k < 16; ++k) {
        int idx = tid + k * 256;
        int d = idx >> 5, j4 = idx & 31;
        float4 x = (k < 8) ? t0p[k] : T0[idx];
        float4 y = (k < 8) ? t1p[k] : T1[idx];
        short4_t o;
        o[0] = f2bf((x.x + y.x) * invqL[j4 * 4 + 0]);
        o[1] = f2bf((x.y + y.y) * invqL[j4 * 4 + 1]);
        o[2] = f2bf((x.z + y.z) * invqL[j4 * 4 + 2]);
        o[3] = f2bf((x.w + y.w) * invqL[j4 * 4 + 3]);
        *(short4_t*)&Bbuf[d * AS + j4 * 4] = o;
    }
    __syncthreads();
    f32x4 accT[8];
    #pragma unroll
    for (int t = 0; t < 8; ++t) accT[t] = (f32x4){0.f,0.f,0.f,0.f};
    #pragma unroll
    for (int ks = 0; ks < 4; ++ks) {
        short8_t a = *(short8_t*)&Abuf[(w * 16 + lm) * AS + ks * 32 + quad * 8];
        #pragma unroll
        for (int dt = 0; dt < 8; ++dt) {
            short8_t bf = *(short8_t*)&Bbuf[(dt * 16 + lm) * AS + ks * 32 + quad * 8];
            accT[dt] = __builtin_amdgcn_mfma_f32_16x16x32_bf16(a, bf, accT[dt], 0, 0, 0);
        }
    }
    __syncthreads();

    // ---- epilogue B: Af32 = accT*rs; store C*Bm ----
    #pragma unroll
    for (int dt = 0; dt < 8; ++dt)
        #pragma unroll
        for (int r = 0; r < 4; ++r)
            Af32[(w * 16 + quad * 4 + r) * AS + dt * 16 + lm] = accT[dt][r] * rs[r];
    __syncthreads();

    #pragma unroll
    for (int k = 0; k < 8; ++k) {
        int idx = tid + k * 256;
        int i = idx >> 5, d4 = idx & 31;
        float4 bm = *(float4*)&Af32[i * AS + d4 * 4];
        float4 c = cv[k];
        size_t base = ((size_t)(b * Lc + i0 + i)) * (4 * Dd) + d4 * 4;
        float4 cb; cb.x = c.x*bm.x; cb.y = c.y*bm.y; cb.z = c.z*bm.z; cb.w = c.w*bm.w;
        *(float4*)&out[base + 3 * Dd]  = cb;
    }
}

extern "C" void kernel_launch(void* const* d_in, const int* in_sizes, int n_in,
                              void* d_out, int out_size, void* d_ws, size_t ws_size,
                              hipStream_t stream) {
    const float* C     = (const float*)d_in[0];
    const float* Q     = (const float*)d_in[1];
    const int*   Cmask = (const int*)d_in[2];
    const int*   Qmask = (const int*)d_in[3];
    const float* w_c   = (const float*)d_in[4];
    const float* w_q   = (const float*)d_in[5];
    const float* w_mul = (const float*)d_in[6];
    const float* bias  = (const float*)d_in[7];
    float* out = (float*)d_out;

    char* p = (char*)d_ws;
    const size_t NQ = (size_t)Bn * Lq * Dd;
    short* Q16   = (short*)p; p += NQ * 2;
    short* QT16  = (short*)p; p += NQ * 2;
    float* Tpart = (float*)p; p += 2 * NQ * 4;
    float* colpart = (float*)p; p += 2 * (size_t)Bn * Lq * 4;
    float* s1f   = (float*)p; p += (size_t)Bn * Lq * 4;

    kT<<<dim3(512), 512, 0, stream>>>(C, Q, Cmask, Qmask, w_c, w_q, w_mul, bias,
                                      Q16, QT16, s1f, Tpart, colpart);
    k3_out<<<dim3(1024), 256, 0, stream>>>(Q16, QT16, Tpart, colpart, C, w_mul, w_c, Qmask,
                                           s1f, bias, out);
}